// Round 2
// baseline (366.394 us; speedup 1.0000x reference)
//
#include <hip/hip_runtime.h>

#define TB 2
#define TT 2048
#define TC 1024
#define TH 16
#define THD 64
#define LNEPS 1e-5f

typedef _Float16 f16;
typedef __attribute__((ext_vector_type(8))) _Float16 f16x8;
typedef __attribute__((ext_vector_type(4))) _Float16 f16x4;
typedef __attribute__((ext_vector_type(4))) float f32x4;

__device__ __forceinline__ f32x4 mfma_16x16x32(f16x8 a, f16x8 b, f32x4 c) {
    return __builtin_amdgcn_mfma_f32_16x16x32_f16(a, b, c, 0, 0, 0);
}

__device__ __forceinline__ void load_lds16(const f16* g, f16* l) {
    __builtin_amdgcn_global_load_lds(
        (const __attribute__((address_space(1))) unsigned int*)g,
        (__attribute__((address_space(3))) unsigned int*)l, 16, 0, 0);
}

// cheap tanh-form GELU: max |err| vs exact erf-GELU ~3e-3 (<< 0.1175 threshold)
__device__ __forceinline__ float gelu_fast(float v) {
    float u = 0.7978845608f * v * (1.f + 0.044715f * v * v);
    float e = exp2f(2.885390082f * u);   // exp(2u) via exp2: saves hidden log2e mul
    return v - v / (e + 1.f);            // == 0.5v(1+tanh(u)); stable at +/-inf
}

// ---------------- LayerNorm: fp32 in -> f16 out, one wave per row (C=1024) ----
__global__ __launch_bounds__(256) void ln_kernel(const float* __restrict__ x,
                                                 const float* __restrict__ w,
                                                 const float* __restrict__ bsrc,
                                                 f16* __restrict__ out) {
    int row  = blockIdx.x * 4 + (threadIdx.x >> 6);
    int lane = threadIdx.x & 63;
    const float4* xr = (const float4*)(x + (size_t)row * TC);
    float4 v[4];
    float s = 0.f, ss = 0.f;
#pragma unroll
    for (int i = 0; i < 4; i++) {
        v[i] = xr[i * 64 + lane];
        s  += v[i].x + v[i].y + v[i].z + v[i].w;
        ss += v[i].x * v[i].x + v[i].y * v[i].y + v[i].z * v[i].z + v[i].w * v[i].w;
    }
#pragma unroll
    for (int off = 32; off > 0; off >>= 1) {
        s  += __shfl_xor(s, off);
        ss += __shfl_xor(ss, off);
    }
    float mean = s * (1.f / TC);
    float var  = ss * (1.f / TC) - mean * mean;
    float rstd = rsqrtf(var + LNEPS);
    const float4* wv = (const float4*)w;
    const float4* bv = (const float4*)bsrc;
    f16x4* ov = (f16x4*)(out + (size_t)row * TC);
#pragma unroll
    for (int i = 0; i < 4; i++) {
        int idx = i * 64 + lane;
        float4 wc = wv[idx], bc = bv[idx];
        f16x4 o;
        o[0] = (f16)((v[i].x - mean) * rstd * wc.x + bc.x);
        o[1] = (f16)((v[i].y - mean) * rstd * wc.y + bc.y);
        o[2] = (f16)((v[i].z - mean) * rstd * wc.z + bc.z);
        o[3] = (f16)((v[i].w - mean) * rstd * wc.w + bc.w);
        ov[idx] = o;
    }
}

// ---------------- fused fp32 -> f16 weight convert ----------------------------
__global__ void cvt_all_kernel(const float* __restrict__ Wq, const float* __restrict__ Wk,
                               const float* __restrict__ Wv, const float* __restrict__ Wp,
                               const float* __restrict__ W1, const float* __restrict__ W2,
                               f16* __restrict__ dst) {
    int i = blockIdx.x * blockDim.x + threadIdx.x;  // x4 units, total 3145728
    const int Q = 262144;                           // 1M elems / 4
    const float* src;
    int j;
    int s = i >> 18;
    if (s < 4) {
        src = (s == 0) ? Wq : (s == 1) ? Wk : (s == 2) ? Wv : Wp;
        j = i & (Q - 1);
    } else if (s < 8) {
        src = W1; j = i - 4 * Q;
    } else {
        src = W2; j = i - 8 * Q;
    }
    float4 v = ((const float4*)src)[j];
    f16x4 o;
    o[0] = (f16)v.x; o[1] = (f16)v.y; o[2] = (f16)v.z; o[3] = (f16)v.w;
    ((f16x4*)dst)[i] = o;
}

// ---------------- legacy GEMM (kept for output projection, EPI 1) -------------
template <int BM, int BN, int BK, int EPI>
__global__ __launch_bounds__(256) void gemm_kernel(const f16* __restrict__ A,
                                                   const f16* __restrict__ W,
                                                   const float* __restrict__ bias,
                                                   const float* __restrict__ bias2,
                                                   const float* __restrict__ bias3,
                                                   const float* __restrict__ res,
                                                   void* __restrict__ outp,
                                                   int M, int N, int K) {
    constexpr int CPR = BK / 8;
    __shared__ __align__(16) f16 sA[BM * BK];
    __shared__ __align__(16) f16 sB[BN * BK];
    const int t  = threadIdx.x;
    const int m0 = blockIdx.y * BM;
    const int n0 = blockIdx.x * BN;
    const int wid = t >> 6, lane = t & 63;
    const int wr = wid >> 1, wc = wid & 1;
    constexpr int WM = BM / 2, WN = BN / 2;
    constexpr int MI = WM / 16, NI = WN / 16;
    f32x4 acc[MI][NI];
#pragma unroll
    for (int i = 0; i < MI; i++)
#pragma unroll
        for (int j = 0; j < NI; j++) acc[i][j] = (f32x4){0.f, 0.f, 0.f, 0.f};
    const int quad = lane >> 4, l15 = lane & 15;

    for (int k0 = 0; k0 < K; k0 += BK) {
#pragma unroll
        for (int i = 0; i < BM * CPR / 256; i++) {
            int p = t + i * 256;
            int row = p / CPR, pc = p % CPR;
            int c = (pc - (row >> 1)) & (CPR - 1);   // inverse swizzle on source
            load_lds16(&A[(size_t)(m0 + row) * K + k0 + c * 8], &sA[p * 8]);
        }
#pragma unroll
        for (int i = 0; i < BN * CPR / 256; i++) {
            int p = t + i * 256;
            int row = p / CPR, pc = p % CPR;
            int c = (pc - (row >> 1)) & (CPR - 1);
            load_lds16(&W[(size_t)(n0 + row) * K + k0 + c * 8], &sB[p * 8]);
        }
        __syncthreads();
#pragma unroll
        for (int ks = 0; ks < BK / 32; ks++) {
            f16x8 af[MI], bf[NI];
#pragma unroll
            for (int i = 0; i < MI; i++) {
                int r = wr * WM + i * 16 + l15;
                af[i] = *(const f16x8*)&sA[(r * CPR + ((ks * 4 + quad + (r >> 1)) & (CPR - 1))) * 8];
            }
#pragma unroll
            for (int j = 0; j < NI; j++) {
                int r = wc * WN + j * 16 + l15;
                bf[j] = *(const f16x8*)&sB[(r * CPR + ((ks * 4 + quad + (r >> 1)) & (CPR - 1))) * 8];
            }
#pragma unroll
            for (int i = 0; i < MI; i++)
#pragma unroll
                for (int j = 0; j < NI; j++)
                    acc[i][j] = mfma_16x16x32(af[i], bf[j], acc[i][j]);
        }
        __syncthreads();
    }

#pragma unroll
    for (int i = 0; i < MI; i++) {
#pragma unroll
        for (int j = 0; j < NI; j++) {
            int col   = n0 + wc * WN + j * 16 + l15;
            int rbase = m0 + wr * WM + i * 16 + quad * 4;
            float bvv = bias ? bias[col] : 0.f;
#pragma unroll
            for (int r = 0; r < 4; r++) {
                size_t idx = (size_t)(rbase + r) * N + col;
                float v = acc[i][j][r] + bvv;
                if constexpr (EPI == 1) {
                    ((float*)outp)[idx] = v + res[idx];
                } else {
                    ((f16*)outp)[idx] = (f16)v;
                }
            }
        }
    }
}

// ---------------- 256x256 8-phase GEMM (T1+T2+T3+T4+T5) -----------------------
// 8 waves (2M x 4N), per-wave C = 128x64. K as 32-wide subtiles in a 4-slot
// LDS ring (A 4x16KB + B 4x16KB = 128 KiB). Per phase: {ds_read frags, issue
// one half-stage (2x global_load_lds), barrier, (compiler-counted lgkm waits),
// setprio(1), 16 MFMA, setprio(0), barrier}. Counted vmcnt(4) once per 2
// subtiles keeps 4 loads in flight across barriers (T4). XCD swizzle (T1):
// contiguous grid chunks per XCD; all grids here have nwg % 8 == 0.
// Chunk-rotation swizzle (c + row>>1)&3 on BOTH global source and ds_read
// address (linear LDS dest per global_load_lds constraint).
#define BARF() do { __builtin_amdgcn_s_barrier(); asm volatile("" ::: "memory"); } while (0)

template <int EPI>
__global__ __launch_bounds__(512, 2) void gemm256_kernel(
    const f16* __restrict__ A, const f16* __restrict__ W,
    const float* __restrict__ bias, const float* __restrict__ bias2,
    const float* __restrict__ bias3,
    f16* __restrict__ out0, f16* __restrict__ out1,
    f16* __restrict__ out2, f16* __restrict__ out3,
    int M, int N, int K) {
    __shared__ __align__(16) f16 lds[8 * 8192];   // 128 KiB
    f16* sA = lds;
    f16* sB = lds + 4 * 8192;
    const int t    = threadIdx.x;
    const int lane = t & 63, wid = t >> 6;
    const int quad = lane >> 4, l15 = lane & 15;
    const int wr = wid >> 2, wc = wid & 3;
    // T1: XCD-aware swizzle of the (x,y) grid; nwg % 8 == 0 for all our grids
    const int gx = gridDim.x;
    const int nwg = gx * gridDim.y;
    int wg = blockIdx.y * gx + blockIdx.x;
    wg = (wg & 7) * (nwg >> 3) + (wg >> 3);
    const int m0 = (wg / gx) * 256, n0 = (wg % gx) * 256;
    int kbeg = 0, nsub = K >> 5;
    f16* outp = out0;
    if constexpr (EPI == 4) {
        int Kc = K >> 2;
        kbeg = blockIdx.z * Kc;
        nsub = Kc >> 5;
        outp = (blockIdx.z == 0) ? out0 : (blockIdx.z == 1) ? out1
             : (blockIdx.z == 2) ? out2 : out3;
    }
    const f16* Abase = A + (size_t)m0 * K + kbeg;
    const f16* Wbase = W + (size_t)n0 * K + kbeg;

    // staging geometry: 1024 16B chunks per 16KB half, 2 per thread
    int srow[2], sgo[2], sld[2];
#pragma unroll
    for (int i = 0; i < 2; i++) {
        int p = t + i * 512;
        int r = p >> 2;
        srow[i] = r;
        sgo[i]  = (((p & 3) - (r >> 1)) & 3) * 8;   // inverse swizzle on source
        sld[i]  = p * 8;                            // linear LDS dest (f16 units)
    }
    auto stageA = [&](int s) {
        if (s >= nsub) return;
        f16* dst = sA + (s & 3) * 8192;
        const f16* src = Abase + s * 32;
#pragma unroll
        for (int i = 0; i < 2; i++)
            load_lds16(src + (size_t)srow[i] * K + sgo[i], dst + sld[i]);
    };
    auto stageB = [&](int s) {
        if (s >= nsub) return;
        f16* dst = sB + (s & 3) * 8192;
        const f16* src = Wbase + s * 32;
#pragma unroll
        for (int i = 0; i < 2; i++)
            load_lds16(src + (size_t)srow[i] * K + sgo[i], dst + sld[i]);
    };

    // fragment-read offsets within a slot (f16 units), swizzled
    int offA[8], offB[4];
#pragma unroll
    for (int q = 0; q < 8; q++) {
        int row = wr * 128 + q * 16 + l15;
        offA[q] = row * 32 + (((quad + (row >> 1)) & 3) * 8);
    }
#pragma unroll
    for (int q = 0; q < 4; q++) {
        int row = wc * 64 + q * 16 + l15;
        offB[q] = row * 32 + (((quad + (row >> 1)) & 3) * 8);
    }

    f32x4 acc[8][4];
#pragma unroll
    for (int i = 0; i < 8; i++)
#pragma unroll
        for (int j = 0; j < 4; j++) acc[i][j] = (f32x4){0.f, 0.f, 0.f, 0.f};

    // prologue: stage subs 0,1,2; wait subs 0,1 resident (sub 2 in flight)
    stageA(0); stageB(0); stageA(1); stageB(1); stageA(2); stageB(2);
    asm volatile("s_waitcnt vmcnt(4)" ::: "memory");
    BARF();

    for (int s = 0; s < nsub; s += 2) {
#pragma unroll
        for (int h = 0; h < 2; h++) {
            const int su = s + h;
            const f16* slA = sA + (su & 3) * 8192;
            const f16* slB = sB + (su & 3) * 8192;
            f16x8 af[4], bf[4];
            // ---- phase rh0: frag-rows 0..3 ----
#pragma unroll
            for (int q = 0; q < 4; q++) af[q] = *(const f16x8*)&slA[offA[q]];
#pragma unroll
            for (int q = 0; q < 4; q++) bf[q] = *(const f16x8*)&slB[offB[q]];
            stageA(su + 3);
            BARF();   // compiler inserts counted lgkm waits before MFMA uses
            __builtin_amdgcn_s_setprio(1);
#pragma unroll
            for (int i = 0; i < 4; i++)
#pragma unroll
                for (int j = 0; j < 4; j++)
                    acc[i][j] = mfma_16x16x32(af[i], bf[j], acc[i][j]);
            __builtin_amdgcn_s_setprio(0);
            BARF();
            // ---- phase rh1: frag-rows 4..7 (bf reused from registers) ----
#pragma unroll
            for (int q = 0; q < 4; q++) af[q] = *(const f16x8*)&slA[offA[4 + q]];
            stageB(su + 3);
            BARF();
            __builtin_amdgcn_s_setprio(1);
#pragma unroll
            for (int i = 0; i < 4; i++)
#pragma unroll
                for (int j = 0; j < 4; j++)
                    acc[4 + i][j] = mfma_16x16x32(af[i], bf[j], acc[4 + i][j]);
            __builtin_amdgcn_s_setprio(0);
            if (h == 1) asm volatile("s_waitcnt vmcnt(4)" ::: "memory");
            BARF();
        }
    }

#pragma unroll
    for (int fr = 0; fr < 8; fr++) {
#pragma unroll
        for (int r = 0; r < 4; r++) {
            int row = m0 + wr * 128 + fr * 16 + quad * 4 + r;
            f16* rowp = outp + (size_t)row * N;
#pragma unroll
            for (int fc = 0; fc < 4; fc++) {
                int col = n0 + wc * 64 + fc * 16 + l15;
                float bvv = 0.f;
                if constexpr (EPI == 3)
                    bvv = (col < 1024) ? bias[col]
                        : (col < 2048) ? bias2[col - 1024] : bias3[col - 2048];
                else if constexpr (EPI == 2)
                    bvv = bias[col];
                float v = acc[fr][fc][r] + bvv;
                if constexpr (EPI == 2) rowp[col] = (f16)gelu_fast(v);
                else                    rowp[col] = (f16)v;
            }
        }
    }
}

// ---------------- split-K=4 reduce: x1 += p0+p1+p2+p3 + b2 --------------------
__global__ __launch_bounds__(256) void reduce4_kernel(const f16* __restrict__ p0,
                                                      const f16* __restrict__ p1,
                                                      const f16* __restrict__ p2,
                                                      const f16* __restrict__ p3,
                                                      const float* __restrict__ b2,
                                                      float* __restrict__ x1) {
    int i = blockIdx.x * 256 + threadIdx.x;     // float4 units over M*N/4 = 1M
    f16x4 a = ((const f16x4*)p0)[i], b = ((const f16x4*)p1)[i];
    f16x4 c = ((const f16x4*)p2)[i], d = ((const f16x4*)p3)[i];
    float4 r = ((float4*)x1)[i];
    float4 bb = ((const float4*)b2)[i & 255];   // N=1024 -> 256 float4/row
    r.x += (float)a[0] + (float)b[0] + (float)c[0] + (float)d[0] + bb.x;
    r.y += (float)a[1] + (float)b[1] + (float)c[1] + (float)d[1] + bb.y;
    r.z += (float)a[2] + (float)b[2] + (float)c[2] + (float)d[2] + bb.z;
    r.w += (float)a[3] + (float)b[3] + (float)c[3] + (float)d[3] + bb.w;
    ((float4*)x1)[i] = r;
}

// ---------------- V transpose: qkv v-slice (stride 3072) -> (B, C, T) f16 -----
__global__ __launch_bounds__(256) void transpose_kernel(const f16* __restrict__ in,
                                                        f16* __restrict__ out) {
    __shared__ f16 tile[32][33];
    int bt = blockIdx.x;
    int b  = bt / (TT / 32);
    int t0 = (bt % (TT / 32)) * 32;
    int c0 = blockIdx.y * 32;
    int tx = threadIdx.x & 31;
    int ty = threadIdx.x >> 5;  // 0..7
    for (int r = ty; r < 32; r += 8)
        tile[r][tx] = in[(size_t)(b * TT + t0 + r) * 3072 + 2048 + c0 + tx];
    __syncthreads();
    for (int r = ty; r < 32; r += 8)
        out[(size_t)(b * TC + c0 + r) * TT + t0 + tx] = tile[tx][r];
}

// ---------------- Block-cooperative flash attention (S^T formulation) ---------
// Softmax: p = exp2(fma(s, log2e, -m*log2e)) (one fma+exp per element);
// T13 defer-max: skip O-rescale/max-update while max drift <= 8 (exact: p/sum
// is invariant to the reference max; e^8 ~ 2981 << f16 max).
__global__ __launch_bounds__(256, 4) void attn_kernel(const f16* __restrict__ qkv,
                                                      const f16* __restrict__ vtg,
                                                      f16* __restrict__ yg) {
    __shared__ __align__(16) f16 sK[2][64 * 64];   // phys chunk = key*8 + (dc ^ (key&7))
    __shared__ __align__(16) f16 sV[2][64 * 64];   // phys chunk = d*8 + (kc ^ (d&7))
    __shared__ __align__(16) f16 pl[4][16 * 64];   // 4e chunk = q*16 + (kq ^ ((q&7)*2))
    const int t    = threadIdx.x;
    const int wid  = t >> 6, lane = t & 63;
    const int quad = lane >> 4, l15 = lane & 15;
    const int idx = blockIdx.x;
    const int u = idx & 255, r = idx >> 8;
    const int bh = u & 31, rc = u >> 5;
    const int qblk = (r == 0) ? rc : (r == 1) ? 31 - rc : (r == 2) ? 8 + rc : 23 - rc;
    const int b = bh >> 4, h = bh & 15;
    const int q0 = qblk * 64;
    const int q0w = q0 + wid * 16;

    const f16* qptr = qkv + (size_t)(b * TT) * 3072 + h * THD;
    const f16* kptr = qptr + 1024;

    f16x8 qa0, qa1;
    {
        const f16* qb_ = qptr + (size_t)(q0w + l15) * 3072 + quad * 8;
        qa0 = *(const f16x8*)qb_;
        qa1 = *(const f16x8*)(qb_ + 32);
#pragma unroll
        for (int j = 0; j < 8; j++) { qa0[j] *= (f16)0.125f; qa1[j] *= (f16)0.125f; }
    }

    auto stage = [&](int buf, int k0) {
#pragma unroll
        for (int i = 0; i < 2; i++) {
            int p = t + i * 256;
            int row = p >> 3, c0 = p & 7;
            int cc = c0 ^ (row & 7);
            load_lds16(kptr + (size_t)(k0 + row) * 3072 + cc * 8, &sK[buf][p * 8]);
            load_lds16(vtg + (size_t)(bh * THD + row) * TT + k0 + cc * 8, &sV[buf][p * 8]);
        }
    };

    f32x4 o[4];
#pragma unroll
    for (int j = 0; j < 4; j++) o[j] = (f32x4){0.f, 0.f, 0.f, 0.f};
    float mcol = -__builtin_inff(), lsum = 0.f;
    f16* plw = pl[wid];
    const int sw = (l15 & 7) << 1;
    const int nt = qblk + 1;

    stage(0, 0);
    for (int it = 0; it < nt; it++) {
        const int cur = it & 1;
        __syncthreads();
        if (it + 1 < nt) stage(cur ^ 1, (it + 1) * 64);
        const int k0 = it * 64;
        if (k0 <= q0w + 15) {
            const f16* sk = sK[cur];
            f32x4 s[4];
            __builtin_amdgcn_s_setprio(1);
#pragma unroll
            for (int g = 0; g < 4; g++) {
                int key = g * 16 + l15;
                f16x8 klo = *(const f16x8*)&sk[(key * 8 + (quad ^ (l15 & 7))) * 8];
                f16x8 khi = *(const f16x8*)&sk[(key * 8 + ((quad + 4) ^ (l15 & 7))) * 8];
                f32x4 a = (f32x4){0.f, 0.f, 0.f, 0.f};
                a = mfma_16x16x32(klo, qa0, a);
                a = mfma_16x16x32(khi, qa1, a);
                s[g] = a;
            }
            __builtin_amdgcn_s_setprio(0);
            const bool full = (k0 + 63 <= q0w);
            float lm = -__builtin_inff();
#pragma unroll
            for (int g = 0; g < 4; g++) {
#pragma unroll
                for (int rr = 0; rr < 4; rr++) {
                    if (!full) {
                        int key = k0 + g * 16 + quad * 4 + rr;
                        if (key > q0w + l15) s[g][rr] = -__builtin_inff();
                    }
                    lm = fmaxf(lm, s[g][rr]);
                }
            }
            lm = fmaxf(lm, __shfl_xor(lm, 16));
            lm = fmaxf(lm, __shfl_xor(lm, 32));
            // T13 defer-max: wave-uniform; exact (ratio invariant to ref max)
            const bool defer = (__all(lm <= mcol + 8.f)) != 0;
            float mnew = defer ? mcol : fmaxf(mcol, lm);
            float ml2  = mnew * 1.44269504f;
            float sum = 0.f;
#pragma unroll
            for (int g = 0; g < 4; g++) {
                f16x4 pw;
#pragma unroll
                for (int rr = 0; rr < 4; rr++) {
                    float p = exp2f(__builtin_fmaf(s[g][rr], 1.44269504f, -ml2));
                    sum += p;
                    pw[rr] = (f16)p;
                }
                *(f16x4*)&plw[(l15 * 16 + ((g * 4 + quad) ^ sw)) * 4] = pw;
            }
            sum += __shfl_xor(sum, 16);
            sum += __shfl_xor(sum, 32);
            if (defer) {
                lsum += sum;
            } else {
                float alpha = __expf(mcol - mnew);
                mcol = mnew;
                lsum = lsum * alpha + sum;
#pragma unroll
                for (int j = 0; j < 4; j++) {
                    o[j][0] *= alpha; o[j][1] *= alpha; o[j][2] *= alpha; o[j][3] *= alpha;
                }
            }
            __asm__ volatile("s_waitcnt lgkmcnt(0)" ::: "memory");
            const f16* sv = sV[cur];
            __builtin_amdgcn_s_setprio(1);
#pragma unroll
            for (int hh = 0; hh < 2; hh++) {
                f16x8 pb = *(const f16x8*)&plw[(l15 * 16 + ((hh * 8 + quad * 2) ^ sw)) * 4];
#pragma unroll
                for (int j = 0; j < 4; j++) {
                    int d = j * 16 + l15;
                    f16x8 vf = *(const f16x8*)&sv[(d * 8 + ((4 * hh + quad) ^ (l15 & 7))) * 8];
                    o[j] = mfma_16x16x32(vf, pb, o[j]);
                }
            }
            __builtin_amdgcn_s_setprio(0);
        }
    }
    float inv = 1.f / lsum;
    size_t rowbase = (size_t)(b * TT + q0w + l15) * TC + h * THD;
#pragma unroll
    for (int j = 0; j < 4; j++) {
        f16x4 ov;
#pragma unroll
        for (int rr = 0; rr < 4; rr++) ov[rr] = (f16)(o[j][rr] * inv);
        *(f16x4*)&yg[rowbase + j * 16 + quad * 4] = ov;
    }
}

// ------------------------------------------------------------------------------
extern "C" void kernel_launch(void* const* d_in, const int* in_sizes, int n_in,
                              void* d_out, int out_size, void* d_ws, size_t ws_size,
                              hipStream_t stream) {
    const float* x    = (const float*)d_in[0];
    const float* ln1w = (const float*)d_in[1];
    const float* ln1b = (const float*)d_in[2];
    const float* ln2w = (const float*)d_in[3];
    const float* ln2b = (const float*)d_in[4];
    const float* Wq   = (const float*)d_in[5];
    const float* bq   = (const float*)d_in[6];
    const float* Wk   = (const float*)d_in[7];
    const float* bk   = (const float*)d_in[8];
    const float* Wv   = (const float*)d_in[9];
    const float* bv   = (const float*)d_in[10];
    const float* Wp   = (const float*)d_in[11];
    const float* bp   = (const float*)d_in[12];
    const float* W1   = (const float*)d_in[13];
    const float* b1   = (const float*)d_in[14];
    const float* W2   = (const float*)d_in[15];
    const float* b2   = (const float*)d_in[16];

    char* ws = (char*)d_ws;
    const size_t MB = 1024 * 1024;
    f16* hb   = (f16*)(ws + 0);          // 8MB  LN1 out; reused as yb, then partial0
    f16* qkv  = (f16*)(ws + 8 * MB);     // 24MB; first 8MB reused as h2b, then partial1
    f16* vT   = (f16*)(ws + 32 * MB);    // 8MB (inside mb's later span -- dead by MLP-up)
    f16* mb   = (f16*)(ws + 16 * MB);    // 32MB (16..48), written post-attention
    f16* Wb   = (f16*)(ws + 48 * MB);    // 24MB f16 weights (48..72)
    f16* Wqb  = Wb;
    f16* Wpb  = Wb + (size_t)3 * 1024 * 1024;
    f16* W1b  = Wb + (size_t)4 * 1024 * 1024;
    f16* W2b  = Wb + (size_t)8 * 1024 * 1024;
    f16* yb   = hb;
    f16* h2b  = qkv;
    // split-K=4 partials: regions dead by MLP-down time
    f16* part0 = (f16*)(ws + 0);         // hb/yb region (dead after out-proj)
    f16* part1 = (f16*)(ws + 8 * MB);    // h2b region (dead after MLP-up)
    f16* part2 = (f16*)(ws + 48 * MB);   // Wq/Wk/Wv/Wp f16 copies (dead after out-proj)
    f16* part3 = (f16*)(ws + 56 * MB);   // W1 f16 copy (dead after MLP-up)
    float* x1 = (float*)d_out;

    cvt_all_kernel<<<12288, 256, 0, stream>>>(Wq, Wk, Wv, Wp, W1, W2, Wb);
    ln_kernel<<<1024, 256, 0, stream>>>(x, ln1w, ln1b, hb);

    // fused QKV projection (256x256 8-phase)
    gemm256_kernel<3><<<dim3(3072 / 256, (TB * TT) / 256), 512, 0, stream>>>(
        hb, Wqb, bq, bk, bv, qkv, nullptr, nullptr, nullptr, TB * TT, 3072, TC);
    transpose_kernel<<<dim3(TB * TT / 32, TC / 32), 256, 0, stream>>>(qkv, vT);
    attn_kernel<<<1024, 256, 0, stream>>>(qkv, vT, yb);
    // output projection + residual -> x1 (legacy 128x64 kernel; N=1024 too small for 256^2)
    gemm_kernel<128, 64, 64, 1><<<dim3(TC / 64, (TB * TT) / 128), 256, 0, stream>>>(
        yb, Wpb, bp, nullptr, nullptr, x, x1, TB * TT, TC, TC);
    ln_kernel<<<1024, 256, 0, stream>>>(x1, ln2w, ln2b, h2b);
    // MLP up + fast GELU (256x256 8-phase)
    gemm256_kernel<2><<<dim3(4 * TC / 256, (TB * TT) / 256), 512, 0, stream>>>(
        h2b, W1b, b1, nullptr, nullptr, mb, nullptr, nullptr, nullptr, TB * TT, 4 * TC, TC);
    // MLP down: split-K=4 f16 partials (256x256 8-phase) + reduce(+bias+residual)
    gemm256_kernel<4><<<dim3(TC / 256, (TB * TT) / 256, 4), 512, 0, stream>>>(
        mb, W2b, nullptr, nullptr, nullptr, part0, part1, part2, part3, TB * TT, TC, 4 * TC);
    reduce4_kernel<<<4096, 256, 0, stream>>>(part0, part1, part2, part3, b2, x1);
}

// Round 3
// 344.525 us; speedup vs baseline: 1.0635x; 1.0635x over previous
//
#include <hip/hip_runtime.h>

#define TB 2
#define TT 2048
#define TC 1024
#define TH 16
#define THD 64
#define LNEPS 1e-5f

typedef _Float16 f16;
typedef __attribute__((ext_vector_type(8))) _Float16 f16x8;
typedef __attribute__((ext_vector_type(4))) _Float16 f16x4;
typedef __attribute__((ext_vector_type(4))) float f32x4;

__device__ __forceinline__ f32x4 mfma_16x16x32(f16x8 a, f16x8 b, f32x4 c) {
    return __builtin_amdgcn_mfma_f32_16x16x32_f16(a, b, c, 0, 0, 0);
}

__device__ __forceinline__ void load_lds16(const f16* g, f16* l) {
    __builtin_amdgcn_global_load_lds(
        (const __attribute__((address_space(1))) unsigned int*)g,
        (__attribute__((address_space(3))) unsigned int*)l, 16, 0, 0);
}

// cheap tanh-form GELU: max |err| vs exact erf-GELU ~3e-3 (<< 0.1175 threshold)
__device__ __forceinline__ float gelu_fast(float v) {
    float u = 0.7978845608f * v * (1.f + 0.044715f * v * v);
    float e = __expf(2.f * u);
    return v - v / (e + 1.f);   // == 0.5v(1+tanh(u)); stable at +/-inf
}

// ---------------- LayerNorm: fp32 in -> f16 out, one wave per row (C=1024) ----
__global__ __launch_bounds__(256) void ln_kernel(const float* __restrict__ x,
                                                 const float* __restrict__ w,
                                                 const float* __restrict__ bsrc,
                                                 f16* __restrict__ out) {
    int row  = blockIdx.x * 4 + (threadIdx.x >> 6);
    int lane = threadIdx.x & 63;
    const float4* xr = (const float4*)(x + (size_t)row * TC);
    float4 v[4];
    float s = 0.f, ss = 0.f;
#pragma unroll
    for (int i = 0; i < 4; i++) {
        v[i] = xr[i * 64 + lane];
        s  += v[i].x + v[i].y + v[i].z + v[i].w;
        ss += v[i].x * v[i].x + v[i].y * v[i].y + v[i].z * v[i].z + v[i].w * v[i].w;
    }
#pragma unroll
    for (int off = 32; off > 0; off >>= 1) {
        s  += __shfl_xor(s, off);
        ss += __shfl_xor(ss, off);
    }
    float mean = s * (1.f / TC);
    float var  = ss * (1.f / TC) - mean * mean;
    float rstd = rsqrtf(var + LNEPS);
    const float4* wv = (const float4*)w;
    const float4* bv = (const float4*)bsrc;
    f16x4* ov = (f16x4*)(out + (size_t)row * TC);
#pragma unroll
    for (int i = 0; i < 4; i++) {
        int idx = i * 64 + lane;
        float4 wc = wv[idx], bc = bv[idx];
        f16x4 o;
        o[0] = (f16)((v[i].x - mean) * rstd * wc.x + bc.x);
        o[1] = (f16)((v[i].y - mean) * rstd * wc.y + bc.y);
        o[2] = (f16)((v[i].z - mean) * rstd * wc.z + bc.z);
        o[3] = (f16)((v[i].w - mean) * rstd * wc.w + bc.w);
        ov[idx] = o;
    }
}

// ---------------- fused fp32 -> f16 weight convert ----------------------------
__global__ void cvt_all_kernel(const float* __restrict__ Wq, const float* __restrict__ Wk,
                               const float* __restrict__ Wv, const float* __restrict__ Wp,
                               const float* __restrict__ W1, const float* __restrict__ W2,
                               f16* __restrict__ dst) {
    int i = blockIdx.x * blockDim.x + threadIdx.x;  // x4 units, total 3145728
    const int Q = 262144;                           // 1M elems / 4
    const float* src;
    int j;
    int s = i >> 18;
    if (s < 4) {
        src = (s == 0) ? Wq : (s == 1) ? Wk : (s == 2) ? Wv : Wp;
        j = i & (Q - 1);
    } else if (s < 8) {
        src = W1; j = i - 4 * Q;
    } else {
        src = W2; j = i - 8 * Q;
    }
    float4 v = ((const float4*)src)[j];
    f16x4 o;
    o[0] = (f16)v.x; o[1] = (f16)v.y; o[2] = (f16)v.z; o[3] = (f16)v.w;
    ((f16x4*)dst)[i] = o;
}

// ---------------- legacy GEMM (kept for output projection, EPI 1) -------------
template <int BM, int BN, int BK, int EPI>
__global__ __launch_bounds__(256) void gemm_kernel(const f16* __restrict__ A,
                                                   const f16* __restrict__ W,
                                                   const float* __restrict__ bias,
                                                   const float* __restrict__ bias2,
                                                   const float* __restrict__ bias3,
                                                   const float* __restrict__ res,
                                                   void* __restrict__ outp,
                                                   int M, int N, int K) {
    constexpr int CPR = BK / 8;
    __shared__ __align__(16) f16 sA[BM * BK];
    __shared__ __align__(16) f16 sB[BN * BK];
    const int t  = threadIdx.x;
    const int m0 = blockIdx.y * BM;
    const int n0 = blockIdx.x * BN;
    const int wid = t >> 6, lane = t & 63;
    const int wr = wid >> 1, wc = wid & 1;
    constexpr int WM = BM / 2, WN = BN / 2;
    constexpr int MI = WM / 16, NI = WN / 16;
    f32x4 acc[MI][NI];
#pragma unroll
    for (int i = 0; i < MI; i++)
#pragma unroll
        for (int j = 0; j < NI; j++) acc[i][j] = (f32x4){0.f, 0.f, 0.f, 0.f};
    const int quad = lane >> 4, l15 = lane & 15;

    for (int k0 = 0; k0 < K; k0 += BK) {
#pragma unroll
        for (int i = 0; i < BM * CPR / 256; i++) {
            int p = t + i * 256;
            int row = p / CPR, pc = p % CPR;
            int c = (pc - (row >> 1)) & (CPR - 1);   // inverse swizzle on source
            load_lds16(&A[(size_t)(m0 + row) * K + k0 + c * 8], &sA[p * 8]);
        }
#pragma unroll
        for (int i = 0; i < BN * CPR / 256; i++) {
            int p = t + i * 256;
            int row = p / CPR, pc = p % CPR;
            int c = (pc - (row >> 1)) & (CPR - 1);
            load_lds16(&W[(size_t)(n0 + row) * K + k0 + c * 8], &sB[p * 8]);
        }
        __syncthreads();
#pragma unroll
        for (int ks = 0; ks < BK / 32; ks++) {
            f16x8 af[MI], bf[NI];
#pragma unroll
            for (int i = 0; i < MI; i++) {
                int r = wr * WM + i * 16 + l15;
                af[i] = *(const f16x8*)&sA[(r * CPR + ((ks * 4 + quad + (r >> 1)) & (CPR - 1))) * 8];
            }
#pragma unroll
            for (int j = 0; j < NI; j++) {
                int r = wc * WN + j * 16 + l15;
                bf[j] = *(const f16x8*)&sB[(r * CPR + ((ks * 4 + quad + (r >> 1)) & (CPR - 1))) * 8];
            }
#pragma unroll
            for (int i = 0; i < MI; i++)
#pragma unroll
                for (int j = 0; j < NI; j++)
                    acc[i][j] = mfma_16x16x32(af[i], bf[j], acc[i][j]);
        }
        __syncthreads();
    }

#pragma unroll
    for (int i = 0; i < MI; i++) {
#pragma unroll
        for (int j = 0; j < NI; j++) {
            int col   = n0 + wc * WN + j * 16 + l15;
            int rbase = m0 + wr * WM + i * 16 + quad * 4;
            float bvv = bias ? bias[col] : 0.f;
#pragma unroll
            for (int r = 0; r < 4; r++) {
                size_t idx = (size_t)(rbase + r) * N + col;
                float v = acc[i][j][r] + bvv;
                if constexpr (EPI == 1) {
                    ((float*)outp)[idx] = v + res[idx];
                } else {
                    ((f16*)outp)[idx] = (f16)v;
                }
            }
        }
    }
}

// ---------------- 256x256 8-phase GEMM (T2+T3+T4+T5) --------------------------
// 8 waves (2M x 4N), per-wave C = 128x64. K as 32-wide subtiles in a 4-slot LDS
// ring (A 4x16KB + B 4x16KB = 128 KiB). Phase pair su: {rh0: ds_read af0-3 +
// bf0-3, issue A(su+3); barrier; lgkm0; 16 MFMA} {rh1: ds_read af4-7, issue
// B(su+3); barrier; lgkm0; 16 MFMA; vmcnt(8)}. The counted vmcnt(8) retires
// sub su+1 exactly one barrier before its first read, leaving subs su+2/su+3
// (8 loads) in flight -> issue-to-wait slack = 4-5 phases (~1400+ cyc at
// target rate) > HBM latency. (Round-1's vmcnt(4) per 4 phases gave only ~2
// phases of slack -> every iteration stalled on load latency; this is the
// T4 counted-vmcnt lesson, m218.) Tail: vmcnt degrades 8->4->0 as stages
// stop being issued (exact accounting; slot-overwrite safety unchanged since
// issue points didn't move). Swizzle: chunk rotation (c + row>>1)&3 on BOTH
// global source and ds_read address (linear LDS dest per global_load_lds).
// EPI 2: f16 = gelu(acc+bias); EPI 3: f16 = acc + qkv-bias-select;
// EPI 4: f16 partial, blockIdx.z selects K-quarter and output pointer.
#define BARF() do { __builtin_amdgcn_s_barrier(); asm volatile("" ::: "memory"); } while (0)

template <int EPI>
__global__ __launch_bounds__(512, 2) void gemm256_kernel(
    const f16* __restrict__ A, const f16* __restrict__ W,
    const float* __restrict__ bias, const float* __restrict__ bias2,
    const float* __restrict__ bias3,
    f16* __restrict__ out0, f16* __restrict__ out1,
    f16* __restrict__ out2, f16* __restrict__ out3,
    int M, int N, int K) {
    __shared__ __align__(16) f16 lds[8 * 8192];   // 128 KiB
    f16* sA = lds;
    f16* sB = lds + 4 * 8192;
    const int t    = threadIdx.x;
    const int lane = t & 63, wid = t >> 6;
    const int quad = lane >> 4, l15 = lane & 15;
    const int wr = wid >> 2, wc = wid & 3;
    const int m0 = blockIdx.y * 256, n0 = blockIdx.x * 256;
    int kbeg = 0, nsub = K >> 5;
    f16* outp = out0;
    if constexpr (EPI == 4) {
        int Kc = K >> 2;
        kbeg = blockIdx.z * Kc;
        nsub = Kc >> 5;
        outp = (blockIdx.z == 0) ? out0 : (blockIdx.z == 1) ? out1
             : (blockIdx.z == 2) ? out2 : out3;
    }
    const f16* Abase = A + (size_t)m0 * K + kbeg;
    const f16* Wbase = W + (size_t)n0 * K + kbeg;

    // staging geometry: 1024 16B chunks per 16KB half, 2 per thread
    int srow[2], sgo[2], sld[2];
#pragma unroll
    for (int i = 0; i < 2; i++) {
        int p = t + i * 512;
        int r = p >> 2;
        srow[i] = r;
        sgo[i]  = (((p & 3) - (r >> 1)) & 3) * 8;   // inverse swizzle on source
        sld[i]  = p * 8;                            // linear LDS dest (f16 units)
    }
    auto stageA = [&](int s) {
        if (s >= nsub) return;
        f16* dst = sA + (s & 3) * 8192;
        const f16* src = Abase + s * 32;
#pragma unroll
        for (int i = 0; i < 2; i++)
            load_lds16(src + (size_t)srow[i] * K + sgo[i], dst + sld[i]);
    };
    auto stageB = [&](int s) {
        if (s >= nsub) return;
        f16* dst = sB + (s & 3) * 8192;
        const f16* src = Wbase + s * 32;
#pragma unroll
        for (int i = 0; i < 2; i++)
            load_lds16(src + (size_t)srow[i] * K + sgo[i], dst + sld[i]);
    };

    // fragment-read offsets within a slot (f16 units), swizzled
    int offA[8], offB[4];
#pragma unroll
    for (int q = 0; q < 8; q++) {
        int row = wr * 128 + q * 16 + l15;
        offA[q] = row * 32 + (((quad + (row >> 1)) & 3) * 8);
    }
#pragma unroll
    for (int q = 0; q < 4; q++) {
        int row = wc * 64 + q * 16 + l15;
        offB[q] = row * 32 + (((quad + (row >> 1)) & 3) * 8);
    }

    f32x4 acc[8][4];
#pragma unroll
    for (int i = 0; i < 8; i++)
#pragma unroll
        for (int j = 0; j < 4; j++) acc[i][j] = (f32x4){0.f, 0.f, 0.f, 0.f};

    // prologue: stage subs 0,1,2 (12 loads); retire sub 0, keep 1,2 in flight
    stageA(0); stageB(0); stageA(1); stageB(1); stageA(2); stageB(2);
    asm volatile("s_waitcnt vmcnt(8)" ::: "memory");
    BARF();

    for (int s = 0; s < nsub; s += 2) {
#pragma unroll
        for (int h = 0; h < 2; h++) {
            const int su = s + h;
            const f16* slA = sA + (su & 3) * 8192;
            const f16* slB = sB + (su & 3) * 8192;
            f16x8 af[4], bf[4];
            // ---- phase rh0: frag-rows 0..3 ----
#pragma unroll
            for (int q = 0; q < 4; q++) af[q] = *(const f16x8*)&slA[offA[q]];
#pragma unroll
            for (int q = 0; q < 4; q++) bf[q] = *(const f16x8*)&slB[offB[q]];
            stageA(su + 3);
            __builtin_amdgcn_s_barrier();
            asm volatile("s_waitcnt lgkmcnt(0)" ::: "memory");
            __builtin_amdgcn_s_setprio(1);
#pragma unroll
            for (int i = 0; i < 4; i++)
#pragma unroll
                for (int j = 0; j < 4; j++)
                    acc[i][j] = mfma_16x16x32(af[i], bf[j], acc[i][j]);
            __builtin_amdgcn_s_setprio(0);
            asm volatile("" ::: "memory");
            BARF();
            // ---- phase rh1: frag-rows 4..7 (bf reused from registers) ----
#pragma unroll
            for (int q = 0; q < 4; q++) af[q] = *(const f16x8*)&slA[offA[4 + q]];
            stageB(su + 3);
            __builtin_amdgcn_s_barrier();
            asm volatile("s_waitcnt lgkmcnt(0)" ::: "memory");
            __builtin_amdgcn_s_setprio(1);
#pragma unroll
            for (int i = 0; i < 4; i++)
#pragma unroll
                for (int j = 0; j < 4; j++)
                    acc[4 + i][j] = mfma_16x16x32(af[i], bf[j], acc[4 + i][j]);
            __builtin_amdgcn_s_setprio(0);
            // counted wait: retire sub su+1 (read next phase-pair); keep
            // su+2, su+3 (8 loads) in flight. Tail degrades 8 -> 4 -> 0.
            if (su + 3 < nsub)      asm volatile("s_waitcnt vmcnt(8)" ::: "memory");
            else if (su + 2 < nsub) asm volatile("s_waitcnt vmcnt(4)" ::: "memory");
            else                    asm volatile("s_waitcnt vmcnt(0)" ::: "memory");
            BARF();
        }
    }

#pragma unroll
    for (int fr = 0; fr < 8; fr++) {
#pragma unroll
        for (int fc = 0; fc < 4; fc++) {
            int col   = n0 + wc * 64 + fc * 16 + l15;
            int rbase = m0 + wr * 128 + fr * 16 + quad * 4;
            float bvv = 0.f;
            if constexpr (EPI == 3)
                bvv = (col < 1024) ? bias[col]
                    : (col < 2048) ? bias2[col - 1024] : bias3[col - 2048];
            else if constexpr (EPI == 2)
                bvv = bias[col];
#pragma unroll
            for (int r = 0; r < 4; r++) {
                size_t idx = (size_t)(rbase + r) * N + col;
                float v = acc[fr][fc][r] + bvv;
                if constexpr (EPI == 2) outp[idx] = (f16)gelu_fast(v);
                else                    outp[idx] = (f16)v;
            }
        }
    }
}

// ---------------- split-K=4 reduce: x1 += p0+p1+p2+p3 + b2 --------------------
__global__ __launch_bounds__(256) void reduce4_kernel(const f16* __restrict__ p0,
                                                      const f16* __restrict__ p1,
                                                      const f16* __restrict__ p2,
                                                      const f16* __restrict__ p3,
                                                      const float* __restrict__ b2,
                                                      float* __restrict__ x1) {
    int i = blockIdx.x * 256 + threadIdx.x;     // float4 units over M*N/4 = 1M
    f16x4 a = ((const f16x4*)p0)[i], b = ((const f16x4*)p1)[i];
    f16x4 c = ((const f16x4*)p2)[i], d = ((const f16x4*)p3)[i];
    float4 r = ((float4*)x1)[i];
    float4 bb = ((const float4*)b2)[i & 255];   // N=1024 -> 256 float4/row
    r.x += (float)a[0] + (float)b[0] + (float)c[0] + (float)d[0] + bb.x;
    r.y += (float)a[1] + (float)b[1] + (float)c[1] + (float)d[1] + bb.y;
    r.z += (float)a[2] + (float)b[2] + (float)c[2] + (float)d[2] + bb.z;
    r.w += (float)a[3] + (float)b[3] + (float)c[3] + (float)d[3] + bb.w;
    ((float4*)x1)[i] = r;
}

// ---------------- V transpose: qkv v-slice (stride 3072) -> (B, C, T) f16 -----
__global__ __launch_bounds__(256) void transpose_kernel(const f16* __restrict__ in,
                                                        f16* __restrict__ out) {
    __shared__ f16 tile[32][33];
    int bt = blockIdx.x;
    int b  = bt / (TT / 32);
    int t0 = (bt % (TT / 32)) * 32;
    int c0 = blockIdx.y * 32;
    int tx = threadIdx.x & 31;
    int ty = threadIdx.x >> 5;  // 0..7
    for (int r = ty; r < 32; r += 8)
        tile[r][tx] = in[(size_t)(b * TT + t0 + r) * 3072 + 2048 + c0 + tx];
    __syncthreads();
    for (int r = ty; r < 32; r += 8)
        out[(size_t)(b * TC + c0 + r) * TT + t0 + tx] = tile[tx][r];
}

// ---------------- Block-cooperative flash attention (S^T formulation) ---------
__global__ __launch_bounds__(256, 4) void attn_kernel(const f16* __restrict__ qkv,
                                                      const f16* __restrict__ vtg,
                                                      f16* __restrict__ yg) {
    __shared__ __align__(16) f16 sK[2][64 * 64];   // phys chunk = key*8 + (dc ^ (key&7))
    __shared__ __align__(16) f16 sV[2][64 * 64];   // phys chunk = d*8 + (kc ^ (d&7))
    __shared__ __align__(16) f16 pl[4][16 * 64];   // 4e chunk = q*16 + (kq ^ ((q&7)*2))
    const int t    = threadIdx.x;
    const int wid  = t >> 6, lane = t & 63;
    const int quad = lane >> 4, l15 = lane & 15;
    const int idx = blockIdx.x;
    const int u = idx & 255, r = idx >> 8;
    const int bh = u & 31, rc = u >> 5;
    const int qblk = (r == 0) ? rc : (r == 1) ? 31 - rc : (r == 2) ? 8 + rc : 23 - rc;
    const int b = bh >> 4, h = bh & 15;
    const int q0 = qblk * 64;
    const int q0w = q0 + wid * 16;

    const f16* qptr = qkv + (size_t)(b * TT) * 3072 + h * THD;
    const f16* kptr = qptr + 1024;

    f16x8 qa0, qa1;
    {
        const f16* qb_ = qptr + (size_t)(q0w + l15) * 3072 + quad * 8;
        qa0 = *(const f16x8*)qb_;
        qa1 = *(const f16x8*)(qb_ + 32);
#pragma unroll
        for (int j = 0; j < 8; j++) { qa0[j] *= (f16)0.125f; qa1[j] *= (f16)0.125f; }
    }

    auto stage = [&](int buf, int k0) {
#pragma unroll
        for (int i = 0; i < 2; i++) {
            int p = t + i * 256;
            int row = p >> 3, c0 = p & 7;
            int cc = c0 ^ (row & 7);
            load_lds16(kptr + (size_t)(k0 + row) * 3072 + cc * 8, &sK[buf][p * 8]);
            load_lds16(vtg + (size_t)(bh * THD + row) * TT + k0 + cc * 8, &sV[buf][p * 8]);
        }
    };

    f32x4 o[4];
#pragma unroll
    for (int j = 0; j < 4; j++) o[j] = (f32x4){0.f, 0.f, 0.f, 0.f};
    float mcol = -__builtin_inff(), lsum = 0.f;
    f16* plw = pl[wid];
    const int sw = (l15 & 7) << 1;
    const int nt = qblk + 1;

    stage(0, 0);
    for (int it = 0; it < nt; it++) {
        const int cur = it & 1;
        __syncthreads();
        if (it + 1 < nt) stage(cur ^ 1, (it + 1) * 64);
        const int k0 = it * 64;
        if (k0 <= q0w + 15) {
            const f16* sk = sK[cur];
            f32x4 s[4];
#pragma unroll
            for (int g = 0; g < 4; g++) {
                int key = g * 16 + l15;
                f16x8 klo = *(const f16x8*)&sk[(key * 8 + (quad ^ (l15 & 7))) * 8];
                f16x8 khi = *(const f16x8*)&sk[(key * 8 + ((quad + 4) ^ (l15 & 7))) * 8];
                f32x4 a = (f32x4){0.f, 0.f, 0.f, 0.f};
                a = mfma_16x16x32(klo, qa0, a);
                a = mfma_16x16x32(khi, qa1, a);
                s[g] = a;
            }
            const bool full = (k0 + 63 <= q0w);
            float lm = -__builtin_inff();
#pragma unroll
            for (int g = 0; g < 4; g++) {
#pragma unroll
                for (int rr = 0; rr < 4; rr++) {
                    if (!full) {
                        int key = k0 + g * 16 + quad * 4 + rr;
                        if (key > q0w + l15) s[g][rr] = -__builtin_inff();
                    }
                    lm = fmaxf(lm, s[g][rr]);
                }
            }
            lm = fmaxf(lm, __shfl_xor(lm, 16));
            lm = fmaxf(lm, __shfl_xor(lm, 32));
            float mnew  = fmaxf(mcol, lm);
            float alpha = __expf(mcol - mnew);
            mcol = mnew;
            float sum = 0.f;
#pragma unroll
            for (int g = 0; g < 4; g++) {
                f16x4 pw;
#pragma unroll
                for (int rr = 0; rr < 4; rr++) {
                    float p = __expf(s[g][rr] - mnew);
                    sum += p;
                    pw[rr] = (f16)p;
                }
                *(f16x4*)&plw[(l15 * 16 + ((g * 4 + quad) ^ sw)) * 4] = pw;
            }
            sum += __shfl_xor(sum, 16);
            sum += __shfl_xor(sum, 32);
            lsum = lsum * alpha + sum;
#pragma unroll
            for (int j = 0; j < 4; j++) {
                o[j][0] *= alpha; o[j][1] *= alpha; o[j][2] *= alpha; o[j][3] *= alpha;
            }
            __asm__ volatile("s_waitcnt lgkmcnt(0)" ::: "memory");
            const f16* sv = sV[cur];
#pragma unroll
            for (int hh = 0; hh < 2; hh++) {
                f16x8 pb = *(const f16x8*)&plw[(l15 * 16 + ((hh * 8 + quad * 2) ^ sw)) * 4];
#pragma unroll
                for (int j = 0; j < 4; j++) {
                    int d = j * 16 + l15;
                    f16x8 vf = *(const f16x8*)&sv[(d * 8 + ((4 * hh + quad) ^ (l15 & 7))) * 8];
                    o[j] = mfma_16x16x32(vf, pb, o[j]);
                }
            }
        }
    }
    float inv = 1.f / lsum;
    size_t rowbase = (size_t)(b * TT + q0w + l15) * TC + h * THD;
#pragma unroll
    for (int j = 0; j < 4; j++) {
        f16x4 ov;
#pragma unroll
        for (int rr = 0; rr < 4; rr++) ov[rr] = (f16)(o[j][rr] * inv);
        *(f16x4*)&yg[rowbase + j * 16 + quad * 4] = ov;
    }
}

// ------------------------------------------------------------------------------
extern "C" void kernel_launch(void* const* d_in, const int* in_sizes, int n_in,
                              void* d_out, int out_size, void* d_ws, size_t ws_size,
                              hipStream_t stream) {
    const float* x    = (const float*)d_in[0];
    const float* ln1w = (const float*)d_in[1];
    const float* ln1b = (const float*)d_in[2];
    const float* ln2w = (const float*)d_in[3];
    const float* ln2b = (const float*)d_in[4];
    const float* Wq   = (const float*)d_in[5];
    const float* bq   = (const float*)d_in[6];
    const float* Wk   = (const float*)d_in[7];
    const float* bk   = (const float*)d_in[8];
    const float* Wv   = (const float*)d_in[9];
    const float* bv   = (const float*)d_in[10];
    const float* Wp   = (const float*)d_in[11];
    const float* bp   = (const float*)d_in[12];
    const float* W1   = (const float*)d_in[13];
    const float* b1   = (const float*)d_in[14];
    const float* W2   = (const float*)d_in[15];
    const float* b2   = (const float*)d_in[16];

    char* ws = (char*)d_ws;
    const size_t MB = 1024 * 1024;
    f16* hb   = (f16*)(ws + 0);          // 8MB  LN1 out; reused as yb, then partial0
    f16* qkv  = (f16*)(ws + 8 * MB);     // 24MB; first 8MB reused as h2b, then partial1
    f16* vT   = (f16*)(ws + 32 * MB);    // 8MB (inside mb's later span -- dead by MLP-up)
    f16* mb   = (f16*)(ws + 16 * MB);    // 32MB (16..48), written post-attention
    f16* Wb   = (f16*)(ws + 48 * MB);    // 24MB f16 weights (48..72)
    f16* Wqb  = Wb;
    f16* Wpb  = Wb + (size_t)3 * 1024 * 1024;
    f16* W1b  = Wb + (size_t)4 * 1024 * 1024;
    f16* W2b  = Wb + (size_t)8 * 1024 * 1024;
    f16* yb   = hb;
    f16* h2b  = qkv;
    // split-K=4 partials: regions dead by MLP-down time
    f16* part0 = (f16*)(ws + 0);         // hb/yb region (dead after out-proj)
    f16* part1 = (f16*)(ws + 8 * MB);    // h2b region (dead after MLP-up)
    f16* part2 = (f16*)(ws + 48 * MB);   // Wq/Wk/Wv/Wp f16 copies (dead after out-proj)
    f16* part3 = (f16*)(ws + 56 * MB);   // W1 f16 copy (dead after MLP-up)
    float* x1 = (float*)d_out;

    cvt_all_kernel<<<12288, 256, 0, stream>>>(Wq, Wk, Wv, Wp, W1, W2, Wb);
    ln_kernel<<<1024, 256, 0, stream>>>(x, ln1w, ln1b, hb);

    // fused QKV projection (256x256 8-phase)
    gemm256_kernel<3><<<dim3(3072 / 256, (TB * TT) / 256), 512, 0, stream>>>(
        hb, Wqb, bq, bk, bv, qkv, nullptr, nullptr, nullptr, TB * TT, 3072, TC);
    transpose_kernel<<<dim3(TB * TT / 32, TC / 32), 256, 0, stream>>>(qkv, vT);
    attn_kernel<<<1024, 256, 0, stream>>>(qkv, vT, yb);
    // output projection + residual -> x1 (legacy 128x64 kernel; N=1024 too small for 256^2)
    gemm_kernel<128, 64, 64, 1><<<dim3(TC / 64, (TB * TT) / 128), 256, 0, stream>>>(
        yb, Wpb, bp, nullptr, nullptr, x, x1, TB * TT, TC, TC);
    ln_kernel<<<1024, 256, 0, stream>>>(x1, ln2w, ln2b, h2b);
    // MLP up + fast GELU (256x256 8-phase)
    gemm256_kernel<2><<<dim3(4 * TC / 256, (TB * TT) / 256), 512, 0, stream>>>(
        h2b, W1b, b1, nullptr, nullptr, mb, nullptr, nullptr, nullptr, TB * TT, 4 * TC, TC);
    // MLP down: split-K=4 f16 partials (256x256 8-phase) + reduce(+bias+residual)
    gemm256_kernel<4><<<dim3(TC / 256, (TB * TT) / 256, 4), 512, 0, stream>>>(
        mb, W2b, nullptr, nullptr, nullptr, part0, part1, part2, part3, TB * TT, TC, 4 * TC);
    reduce4_kernel<<<4096, 256, 0, stream>>>(part0, part1, part2, part3, b2, x1);
}